// Round 3
// baseline (2540.261 us; speedup 1.0000x reference)
//
#include <hip/hip_runtime.h>
#include <stdint.h>

// TinyGRU fused: both GRU layers in ONE kernel, 16 chains/block (32 blocks).
// Layer1 runs one timestep behind layer0 (software pipeline): at iter u,
// layer0 computes h0[u] and layer1 computes h1[u-1], both via
// v_mfma_f32_16x16x32_f16 on [16x128]x[128x384] tiles. h0 stream lives only
// in LDS (s_x1) -> NO global stores in the loop (barrier won't drain vmcnt).
// Layer0's h-fragment read (h0[u-1]) doubles as layer1's x-fragment input.
// x staged in 4-step chunks via a register queue loaded one chunk ahead
// (~4 iters of slack >> 900cyc HBM latency). One barrier per iteration.

typedef _Float16 half_t;
typedef _Float16 half8 __attribute__((ext_vector_type(8)));
typedef float f32x4 __attribute__((ext_vector_type(4)));

#define SS 1024
#define CPB 16           // chains per block
#define NBLK 32          // 512 / CPB
#define CT 4             // x chunk steps (register queue depth)
#define HST 136          // padded LDS row stride, 128-wide (f16 elems)
#define XST 72           // padded LDS row stride, 64-wide (f16 elems)

#define MFMA16(a, b, c) __builtin_amdgcn_mfma_f32_16x16x32_f16(a, b, c, 0, 0, 0)

__device__ __forceinline__ float sigmoidf_(float x) {
    return __builtin_amdgcn_rcpf(1.0f + __expf(-x));
}
__device__ __forceinline__ float tanhf_(float x) {
    return 1.0f - 2.0f * __builtin_amdgcn_rcpf(1.0f + __expf(2.0f * x));
}
__device__ __forceinline__ half8 cvt8(const float* p) {
    f32x4 a = *(const f32x4*)p;
    f32x4 b = *(const f32x4*)(p + 4);
    half8 r;
    r[0] = (half_t)a[0]; r[1] = (half_t)a[1]; r[2] = (half_t)a[2]; r[3] = (half_t)a[3];
    r[4] = (half_t)b[0]; r[5] = (half_t)b[1]; r[6] = (half_t)b[2]; r[7] = (half_t)b[3];
    return r;
}

__global__ __launch_bounds__(512, 2)
void gru_fused(const float* __restrict__ x,
               const float* __restrict__ Wih0, const float* __restrict__ Whh0,
               const float* __restrict__ bih0, const float* __restrict__ bhh0,
               const float* __restrict__ Wih1, const float* __restrict__ Whh1,
               const float* __restrict__ bih1, const float* __restrict__ bhh1,
               const float* __restrict__ fcw, const float* __restrict__ fcb,
               float* __restrict__ out)
{
    const int tid  = threadIdx.x;
    const int w    = tid >> 6;          // wave = gate-col slice 0..7
    const int lane = tid & 63;
    const int quad = lane >> 4;
    const int col  = lane & 15;
    const int cb   = blockIdx.x * CPB;

    __shared__ alignas(16) half_t s_x0[2][CT][CPB * XST]; // x chunks (f16)
    __shared__ alignas(16) half_t s_x1[2][CPB * HST];     // h0 stream
    __shared__ alignas(16) half_t s_h1[2][CPB * HST];     // h1 stream

    // ---- weights into register B-fragments (reused 1024x) ----
    const int rr = w * 16 + col;        // this lane's gate-row (within gate)
    half8 B0xr[2], B0xz[2], B0xn[2];    // layer0 Wih (K=64)
    half8 B0hr[4], B0hz[4], B0hn[4];    // layer0 Whh (K=128)
    half8 B1xr[4], B1xz[4], B1xn[4];    // layer1 Wih (K=128)
    half8 B1hr[4], B1hz[4], B1hn[4];    // layer1 Whh (K=128)
#pragma unroll
    for (int s = 0; s < 2; ++s) {
        B0xr[s] = cvt8(Wih0 + (rr      ) * 64 + s * 32 + quad * 8);
        B0xz[s] = cvt8(Wih0 + (rr + 128) * 64 + s * 32 + quad * 8);
        B0xn[s] = cvt8(Wih0 + (rr + 256) * 64 + s * 32 + quad * 8);
    }
#pragma unroll
    for (int s = 0; s < 4; ++s) {
        B0hr[s] = cvt8(Whh0 + (rr      ) * 128 + s * 32 + quad * 8);
        B0hz[s] = cvt8(Whh0 + (rr + 128) * 128 + s * 32 + quad * 8);
        B0hn[s] = cvt8(Whh0 + (rr + 256) * 128 + s * 32 + quad * 8);
        B1xr[s] = cvt8(Wih1 + (rr      ) * 128 + s * 32 + quad * 8);
        B1xz[s] = cvt8(Wih1 + (rr + 128) * 128 + s * 32 + quad * 8);
        B1xn[s] = cvt8(Wih1 + (rr + 256) * 128 + s * 32 + quad * 8);
        B1hr[s] = cvt8(Whh1 + (rr      ) * 128 + s * 32 + quad * 8);
        B1hz[s] = cvt8(Whh1 + (rr + 128) * 128 + s * 32 + quad * 8);
        B1hn[s] = cvt8(Whh1 + (rr + 256) * 128 + s * 32 + quad * 8);
    }
    const float b0r  = bih0[rr] + bhh0[rr];
    const float b0z  = bih0[128 + rr] + bhh0[128 + rr];
    const float b0ni = bih0[256 + rr];
    const float b0nh = bhh0[256 + rr];
    const float b1r  = bih1[rr] + bhh1[rr];
    const float b1z  = bih1[128 + rr] + bhh1[128 + rr];
    const float b1ni = bih1[256 + rr];
    const float b1nh = bhh1[256 + rr];

    // init: h0[-1] = 0 (s_x1[0]), h1[-1] = 0 (s_h1[1])
    for (int i = tid; i < CPB * HST; i += 512) {
        s_x1[0][i] = (half_t)0.0f;
        s_h1[1][i] = (half_t)0.0f;
    }

    // ---- x staging: thread -> (chain sm, col-pair sc2), 4-step reg queue ----
    const int sm  = tid >> 5;
    const int sc2 = (tid & 31) * 2;
    const float* xrow = x + (size_t)(cb + sm) * SS * 64 + sc2;
    float2 gq[CT];
#pragma unroll
    for (int i = 0; i < CT; ++i) gq[i] = *(const float2*)(xrow + i * 64);
#pragma unroll
    for (int i = 0; i < CT; ++i) {      // publish chunk 0
        s_x0[0][i][sm * XST + sc2]     = (half_t)gq[i].x;
        s_x0[0][i][sm * XST + sc2 + 1] = (half_t)gq[i].y;
    }
#pragma unroll
    for (int i = 0; i < CT; ++i)        // issue chunk 1
        gq[i] = *(const float2*)(xrow + (CT + i) * 64);
    __syncthreads();

    float hp0[4] = {0.f, 0.f, 0.f, 0.f};
    float hp1[4] = {0.f, 0.f, 0.f, 0.f};
    const int hcol = rr;
    const int aoff = col * HST + quad * 8;   // h-fragment base (f16 elems)

    // ================= iter u=0: layer0 only =================
    {
        half8 ah0[4];
#pragma unroll
        for (int s = 0; s < 4; ++s)
            ah0[s] = *(const half8*)&s_x1[0][aoff + s * 32];
        f32x4 ar = {b0r, b0r, b0r, b0r}, az = {b0z, b0z, b0z, b0z};
        f32x4 ani = {b0ni, b0ni, b0ni, b0ni}, anh = {b0nh, b0nh, b0nh, b0nh};
#pragma unroll
        for (int s = 0; s < 2; ++s) {
            half8 ax = *(const half8*)&s_x0[0][0][col * XST + s * 32 + quad * 8];
            ar  = MFMA16(ax, B0xr[s], ar);
            az  = MFMA16(ax, B0xz[s], az);
            ani = MFMA16(ax, B0xn[s], ani);
        }
#pragma unroll
        for (int s = 0; s < 4; ++s) {
            ar  = MFMA16(ah0[s], B0hr[s], ar);
            az  = MFMA16(ah0[s], B0hz[s], az);
            anh = MFMA16(ah0[s], B0hn[s], anh);
        }
#pragma unroll
        for (int i = 0; i < 4; ++i) {
            float r = sigmoidf_(ar[i]);
            float z = sigmoidf_(az[i]);
            float n = tanhf_(ani[i] + r * anh[i]);
            float h = (1.0f - z) * n + z * hp0[i];
            hp0[i] = h;
            s_x1[1][(quad * 4 + i) * HST + hcol] = (half_t)h;
        }
        __syncthreads();
    }

    // ================= main loop u = 1..1023: both layers =================
    for (int u = 1; u < SS; ++u) {
        const int cur = u & 1, nxt = cur ^ 1;

        // shared fragment: h0[u-1] (layer0 h-input AND layer1 x-input)
        half8 ah0[4], ah1[4];
#pragma unroll
        for (int s = 0; s < 4; ++s) {
            ah0[s] = *(const half8*)&s_x1[cur][aoff + s * 32];
            ah1[s] = *(const half8*)&s_h1[cur][aoff + s * 32];
        }

        // ---- layer0: h0[u] ----
        f32x4 ar0 = {b0r, b0r, b0r, b0r}, az0 = {b0z, b0z, b0z, b0z};
        f32x4 ani0 = {b0ni, b0ni, b0ni, b0ni}, anh0 = {b0nh, b0nh, b0nh, b0nh};
#pragma unroll
        for (int s = 0; s < 2; ++s) {
            half8 ax = *(const half8*)&s_x0[(u >> 2) & 1][u & 3]
                                          [col * XST + s * 32 + quad * 8];
            ar0  = MFMA16(ax, B0xr[s], ar0);
            az0  = MFMA16(ax, B0xz[s], az0);
            ani0 = MFMA16(ax, B0xn[s], ani0);
        }
        // ---- layer1: h1[u-1] (independent of layer0 -> ILP) ----
        f32x4 ar1 = {b1r, b1r, b1r, b1r}, az1 = {b1z, b1z, b1z, b1z};
        f32x4 ani1 = {b1ni, b1ni, b1ni, b1ni}, anh1 = {b1nh, b1nh, b1nh, b1nh};
#pragma unroll
        for (int s = 0; s < 4; ++s) {
            ar0  = MFMA16(ah0[s], B0hr[s], ar0);
            az0  = MFMA16(ah0[s], B0hz[s], az0);
            anh0 = MFMA16(ah0[s], B0hn[s], anh0);
            ar1  = MFMA16(ah0[s], B1xr[s], ar1);
            az1  = MFMA16(ah0[s], B1xz[s], az1);
            ani1 = MFMA16(ah0[s], B1xn[s], ani1);
            ar1  = MFMA16(ah1[s], B1hr[s], ar1);
            az1  = MFMA16(ah1[s], B1hz[s], az1);
            anh1 = MFMA16(ah1[s], B1hn[s], anh1);
        }
#pragma unroll
        for (int i = 0; i < 4; ++i) {
            float r = sigmoidf_(ar0[i]);
            float z = sigmoidf_(az0[i]);
            float n = tanhf_(ani0[i] + r * anh0[i]);
            float h = (1.0f - z) * n + z * hp0[i];
            hp0[i] = h;
            s_x1[nxt][(quad * 4 + i) * HST + hcol] = (half_t)h;
        }
#pragma unroll
        for (int i = 0; i < 4; ++i) {
            float r = sigmoidf_(ar1[i]);
            float z = sigmoidf_(az1[i]);
            float n = tanhf_(ani1[i] + r * anh1[i]);
            float h = (1.0f - z) * n + z * hp1[i];
            hp1[i] = h;
            s_h1[nxt][(quad * 4 + i) * HST + hcol] = (half_t)h;
        }

        // ---- x chunk refill: publish chunk (u+1)/CT, issue chunk +1 ----
        if ((u & 3) == 3 && u + 1 < SS) {
            const int c1 = (u + 1) >> 2;
#pragma unroll
            for (int i = 0; i < CT; ++i) {
                s_x0[c1 & 1][i][sm * XST + sc2]     = (half_t)gq[i].x;
                s_x0[c1 & 1][i][sm * XST + sc2 + 1] = (half_t)gq[i].y;
            }
            const int base = (c1 + 1) * CT;
            if (base < SS) {
#pragma unroll
                for (int i = 0; i < CT; ++i)
                    gq[i] = *(const float2*)(xrow + (size_t)(base + i) * 64);
            }
        }
        __syncthreads();
    }

    // ================= iter u=1024: layer1 only (h1[1023]) =================
    {
        half8 ah0[4], ah1[4];
#pragma unroll
        for (int s = 0; s < 4; ++s) {
            ah0[s] = *(const half8*)&s_x1[0][aoff + s * 32];  // h0[1023]
            ah1[s] = *(const half8*)&s_h1[0][aoff + s * 32];  // h1[1022]
        }
        f32x4 ar1 = {b1r, b1r, b1r, b1r}, az1 = {b1z, b1z, b1z, b1z};
        f32x4 ani1 = {b1ni, b1ni, b1ni, b1ni}, anh1 = {b1nh, b1nh, b1nh, b1nh};
#pragma unroll
        for (int s = 0; s < 4; ++s) {
            ar1  = MFMA16(ah0[s], B1xr[s], ar1);
            az1  = MFMA16(ah0[s], B1xz[s], az1);
            ani1 = MFMA16(ah0[s], B1xn[s], ani1);
            ar1  = MFMA16(ah1[s], B1hr[s], ar1);
            az1  = MFMA16(ah1[s], B1hz[s], az1);
            anh1 = MFMA16(ah1[s], B1hn[s], anh1);
        }
#pragma unroll
        for (int i = 0; i < 4; ++i) {
            float r = sigmoidf_(ar1[i]);
            float z = sigmoidf_(az1[i]);
            float n = tanhf_(ani1[i] + r * anh1[i]);
            float h = (1.0f - z) * n + z * hp1[i];
            s_h1[1][(quad * 4 + i) * HST + hcol] = (half_t)h;
        }
        __syncthreads();
    }

    // ---- FC epilogue: out[b,c] = fc_w[c,:] . h1_final + fc_b[c] ----
    if (tid < 160) {
        const int ch = tid / 10, cl = tid - ch * 10;
        float acc = fcb[cl];
        const float* wr = fcw + cl * 128;
        const half_t* hv = &s_h1[1][ch * HST];
#pragma unroll 8
        for (int k = 0; k < 128; ++k) acc += (float)hv[k] * wr[k];
        out[(cb + ch) * 10 + cl] = acc;
    }
}

extern "C" void kernel_launch(void* const* d_in, const int* in_sizes, int n_in,
                              void* d_out, int out_size, void* d_ws, size_t ws_size,
                              hipStream_t stream) {
    const float* x    = (const float*)d_in[0];
    const float* Wih0 = (const float*)d_in[1];
    const float* Whh0 = (const float*)d_in[2];
    const float* bih0 = (const float*)d_in[3];
    const float* bhh0 = (const float*)d_in[4];
    const float* Wih1 = (const float*)d_in[5];
    const float* Whh1 = (const float*)d_in[6];
    const float* bih1 = (const float*)d_in[7];
    const float* bhh1 = (const float*)d_in[8];
    const float* fcw  = (const float*)d_in[9];
    const float* fcb  = (const float*)d_in[10];

    gru_fused<<<NBLK, 512, 0, stream>>>(x, Wih0, Whh0, bih0, bhh0,
                                        Wih1, Whh1, bih1, bhh1,
                                        fcw, fcb, (float*)d_out);
}

// Round 4
// 1222.427 us; speedup vs baseline: 2.0780x; 2.0780x over previous
//
#include <hip/hip_runtime.h>
#include <stdint.h>

// TinyGRU, split MFMA kernels, CPB=4: 128 blocks/kernel (128 CUs busy).
// Chain c occupies MFMA tile row 4c (= quad c, reg 0 in D-layout
// row=quad*4+reg), so gate math is exactly ONE element per lane (full exec):
// transcendental issue drops 4x vs CPB=16 while per-wave MFMA count is
// unchanged. Fragment math identical to the verified R1 kernel.
// h double-buffered in LDS (one barrier/step); weights in register
// B-fragments reused 1024x; x staged via 4-step register queue.

typedef _Float16 half_t;
typedef _Float16 half8 __attribute__((ext_vector_type(8)));
typedef float f32x4 __attribute__((ext_vector_type(4)));

#define SS 1024
#define CPB 4            // chains per block
#define NBLK 128         // 512 / CPB
#define CT 4             // x chunk steps (register queue depth)
#define HST 136          // padded LDS row stride, 128-wide (f16 elems)
#define XST 72           // padded LDS row stride, 64-wide (f16 elems)

#define MFMA16(a, b, c) __builtin_amdgcn_mfma_f32_16x16x32_f16(a, b, c, 0, 0, 0)

__device__ __forceinline__ float sigmoidf_(float x) {
    return __builtin_amdgcn_rcpf(1.0f + __expf(-x));
}
__device__ __forceinline__ float tanhf_(float x) {
    return 1.0f - 2.0f * __builtin_amdgcn_rcpf(1.0f + __expf(2.0f * x));
}
__device__ __forceinline__ half8 cvt8(const float* p) {
    f32x4 a = *(const f32x4*)p;
    f32x4 b = *(const f32x4*)(p + 4);
    half8 r;
    r[0] = (half_t)a[0]; r[1] = (half_t)a[1]; r[2] = (half_t)a[2]; r[3] = (half_t)a[3];
    r[4] = (half_t)b[0]; r[5] = (half_t)b[1]; r[6] = (half_t)b[2]; r[7] = (half_t)b[3];
    return r;
}

// ---------------- Layer 0: x[B,S,64] f32 -> h1[B,S,128] f16 ----------------
__global__ __launch_bounds__(512, 2)
void gru_rec0(const float* __restrict__ x, const float* __restrict__ Wih,
              const float* __restrict__ Whh, const float* __restrict__ bih,
              const float* __restrict__ bhh, half_t* __restrict__ h1)
{
    const int tid  = threadIdx.x;
    const int w    = tid >> 6;          // wave = gate-col slice 0..7
    const int lane = tid & 63;
    const int quad = lane >> 4;
    const int col  = lane & 15;
    const int cb   = blockIdx.x * CPB;

    __shared__ alignas(16) half_t s_x[2][CT][16 * XST];
    __shared__ alignas(16) half_t s_h[2][16 * HST];

    const int rr = w * 16 + col;        // this lane's gate-row (within gate)
    half8 Bxr[2], Bxz[2], Bxn[2];       // Wih (K=64)
    half8 Bhr[4], Bhz[4], Bhn[4];       // Whh (K=128)
#pragma unroll
    for (int s = 0; s < 2; ++s) {
        Bxr[s] = cvt8(Wih + (rr      ) * 64 + s * 32 + quad * 8);
        Bxz[s] = cvt8(Wih + (rr + 128) * 64 + s * 32 + quad * 8);
        Bxn[s] = cvt8(Wih + (rr + 256) * 64 + s * 32 + quad * 8);
    }
#pragma unroll
    for (int s = 0; s < 4; ++s) {
        Bhr[s] = cvt8(Whh + (rr      ) * 128 + s * 32 + quad * 8);
        Bhz[s] = cvt8(Whh + (rr + 128) * 128 + s * 32 + quad * 8);
        Bhn[s] = cvt8(Whh + (rr + 256) * 128 + s * 32 + quad * 8);
    }
    const float br  = bih[rr] + bhh[rr];
    const float bz  = bih[128 + rr] + bhh[128 + rr];
    const float bni = bih[256 + rr];
    const float bnh = bhh[256 + rr];

    // zero all LDS rows once (unused rows stay 0 forever)
    for (int i = tid; i < 2 * CT * 16 * XST; i += 512) ((half_t*)s_x)[i] = (half_t)0.0f;
    for (int i = tid; i < 2 * 16 * HST; i += 512)      ((half_t*)s_h)[i] = (half_t)0.0f;
    __syncthreads();

    // ---- x staging: tid<256 -> (chain c=tid>>6, col sc=tid&63) ----
    const int c  = (tid >> 6) & 3;
    const int sc = tid & 63;
    const float* xrow = x + (size_t)(cb + c) * SS * 64 + sc;
    float gq[CT];
    if (tid < 256) {
#pragma unroll
        for (int i = 0; i < CT; ++i) gq[i] = xrow[i * 64];
#pragma unroll
        for (int i = 0; i < CT; ++i)            // publish chunk 0
            s_x[0][i][4 * c * XST + sc] = (half_t)gq[i];
#pragma unroll
        for (int i = 0; i < CT; ++i)            // issue chunk 1
            gq[i] = xrow[(CT + i) * 64];
    }
    __syncthreads();

    float hp = 0.0f;                            // chain = quad, reg 0
    const int aoff = col * HST + quad * 8;
    uint32_t* h1u = (uint32_t*)(h1 + (size_t)(cb + c) * SS * 128) + sc;

    for (int t = 0; t < SS; ++t) {
        const int cur = t & 1, nxt = cur ^ 1;

        // write h_{t-1} (stable in s_h[cur]) to global, 2 cols per thread
        if (t >= 1 && tid < 256) {
            uint32_t v = *(const uint32_t*)&s_h[cur][4 * c * HST + 2 * sc];
            h1u[(size_t)(t - 1) * 64] = v;
        }

        f32x4 ar  = {br, br, br, br},     az  = {bz, bz, bz, bz};
        f32x4 ani = {bni, bni, bni, bni}, anh = {bnh, bnh, bnh, bnh};
#pragma unroll
        for (int s = 0; s < 2; ++s) {           // x-contribution (K=64)
            half8 ax = *(const half8*)&s_x[(t >> 2) & 1][t & 3]
                                          [col * XST + s * 32 + quad * 8];
            ar  = MFMA16(ax, Bxr[s], ar);
            az  = MFMA16(ax, Bxz[s], az);
            ani = MFMA16(ax, Bxn[s], ani);
        }
#pragma unroll
        for (int s = 0; s < 4; ++s) {           // h-contribution (K=128)
            half8 ah = *(const half8*)&s_h[cur][aoff + s * 32];
            ar  = MFMA16(ah, Bhr[s], ar);
            az  = MFMA16(ah, Bhz[s], az);
            anh = MFMA16(ah, Bhn[s], anh);
        }
        {   // gate math: ONE element per lane (chain=quad lives in reg 0)
            float r = sigmoidf_(ar[0]);
            float z = sigmoidf_(az[0]);
            float n = tanhf_(ani[0] + r * anh[0]);
            hp = n + z * (hp - n);
            s_h[nxt][4 * quad * HST + rr] = (half_t)hp;
        }
        // x chunk refill every 4 steps
        if ((t & 3) == 3 && t + 1 < SS && tid < 256) {
            const int c1 = (t + 1) >> 2;
#pragma unroll
            for (int i = 0; i < CT; ++i)
                s_x[c1 & 1][i][4 * c * XST + sc] = (half_t)gq[i];
            const int base = (c1 + 1) * CT;
            if (base < SS) {
#pragma unroll
                for (int i = 0; i < CT; ++i)
                    gq[i] = xrow[(size_t)(base + i) * 64];
            }
        }
        __syncthreads();
    }
    if (tid < 256) {    // final h_{1023} sits in s_h[0]
        uint32_t v = *(const uint32_t*)&s_h[0][4 * c * HST + 2 * sc];
        h1u[(size_t)(SS - 1) * 64] = v;
    }
}

// ------------- Layer 1: h1[B,S,128] f16 -> FC -> out[B,10] f32 -------------
__global__ __launch_bounds__(512, 2)
void gru_rec1(const half_t* __restrict__ h1, const float* __restrict__ Wih,
              const float* __restrict__ Whh, const float* __restrict__ bih,
              const float* __restrict__ bhh, const float* __restrict__ fcw,
              const float* __restrict__ fcb, float* __restrict__ out)
{
    const int tid  = threadIdx.x;
    const int w    = tid >> 6;
    const int lane = tid & 63;
    const int quad = lane >> 4;
    const int col  = lane & 15;
    const int cb   = blockIdx.x * CPB;

    __shared__ alignas(16) half_t s_x[2][16 * HST];
    __shared__ alignas(16) half_t s_h[2][16 * HST];

    const int rr = w * 16 + col;
    half8 Bxr[4], Bxz[4], Bxn[4];       // Wih (K=128)
    half8 Bhr[4], Bhz[4], Bhn[4];       // Whh (K=128)
#pragma unroll
    for (int s = 0; s < 4; ++s) {
        Bxr[s] = cvt8(Wih + (rr      ) * 128 + s * 32 + quad * 8);
        Bxz[s] = cvt8(Wih + (rr + 128) * 128 + s * 32 + quad * 8);
        Bxn[s] = cvt8(Wih + (rr + 256) * 128 + s * 32 + quad * 8);
        Bhr[s] = cvt8(Whh + (rr      ) * 128 + s * 32 + quad * 8);
        Bhz[s] = cvt8(Whh + (rr + 128) * 128 + s * 32 + quad * 8);
        Bhn[s] = cvt8(Whh + (rr + 256) * 128 + s * 32 + quad * 8);
    }
    const float br  = bih[rr] + bhh[rr];
    const float bz  = bih[128 + rr] + bhh[128 + rr];
    const float bni = bih[256 + rr];
    const float bnh = bhh[256 + rr];

    for (int i = tid; i < 2 * 16 * HST; i += 512) {
        ((half_t*)s_x)[i] = (half_t)0.0f;
        ((half_t*)s_h)[i] = (half_t)0.0f;
    }
    __syncthreads();

    // staging: tid<256 -> (chain c, col-pair sc), 4B per thread per step
    const int c  = (tid >> 6) & 3;
    const int sc = tid & 63;
    const uint32_t* xrow = (const uint32_t*)(h1 + (size_t)(cb + c) * SS * 128) + sc;
    if (tid < 256) {    // stage x_0
        uint32_t g0 = xrow[0];
        *(uint32_t*)&s_x[0][4 * c * HST + 2 * sc] = g0;
    }
    __syncthreads();

    float hp = 0.0f;
    const int aoff = col * HST + quad * 8;

    for (int t = 0; t < SS; ++t) {
        const int cur = t & 1, nxt = cur ^ 1;

        uint32_t g = 0u;
        const bool pf = (tid < 256) && (t + 1 < SS);
        if (pf) g = xrow[(size_t)(t + 1) * 64];

        f32x4 ar  = {br, br, br, br},     az  = {bz, bz, bz, bz};
        f32x4 ani = {bni, bni, bni, bni}, anh = {bnh, bnh, bnh, bnh};
#pragma unroll
        for (int s = 0; s < 4; ++s) {
            half8 ax = *(const half8*)&s_x[cur][col * HST + s * 32 + quad * 8];
            half8 ah = *(const half8*)&s_h[cur][aoff + s * 32];
            ar  = MFMA16(ax, Bxr[s], ar);
            ar  = MFMA16(ah, Bhr[s], ar);
            az  = MFMA16(ax, Bxz[s], az);
            az  = MFMA16(ah, Bhz[s], az);
            ani = MFMA16(ax, Bxn[s], ani);
            anh = MFMA16(ah, Bhn[s], anh);
        }
        {   // gate math: one element per lane (chain=quad, reg 0)
            float r = sigmoidf_(ar[0]);
            float z = sigmoidf_(az[0]);
            float n = tanhf_(ani[0] + r * anh[0]);
            hp = n + z * (hp - n);
            s_h[nxt][4 * quad * HST + rr] = (half_t)hp;
        }
        if (pf) *(uint32_t*)&s_x[nxt][4 * c * HST + 2 * sc] = g;
        __syncthreads();
    }

    // FC epilogue: h_final in s_h[0] (SS even). 4 chains x 10 outputs.
    if (tid < 40) {
        const int ch = tid / 10, cl = tid - ch * 10;
        float acc = fcb[cl];
        const float* wr = fcw + cl * 128;
        const half_t* hv = &s_h[0][4 * ch * HST];
#pragma unroll 8
        for (int k = 0; k < 128; ++k) acc += (float)hv[k] * wr[k];
        out[(cb + ch) * 10 + cl] = acc;
    }
}

extern "C" void kernel_launch(void* const* d_in, const int* in_sizes, int n_in,
                              void* d_out, int out_size, void* d_ws, size_t ws_size,
                              hipStream_t stream) {
    const float* x    = (const float*)d_in[0];
    const float* Wih0 = (const float*)d_in[1];
    const float* Whh0 = (const float*)d_in[2];
    const float* bih0 = (const float*)d_in[3];
    const float* bhh0 = (const float*)d_in[4];
    const float* Wih1 = (const float*)d_in[5];
    const float* Whh1 = (const float*)d_in[6];
    const float* bih1 = (const float*)d_in[7];
    const float* bhh1 = (const float*)d_in[8];
    const float* fcw  = (const float*)d_in[9];
    const float* fcb  = (const float*)d_in[10];

    half_t* h1 = (half_t*)d_ws;   // [512,1024,128] f16 = 134 MB

    gru_rec0<<<NBLK, 512, 0, stream>>>(x, Wih0, Whh0, bih0, bhh0, h1);
    gru_rec1<<<NBLK, 512, 0, stream>>>(h1, Wih1, Whh1, bih1, bhh1, fcw, fcb,
                                       (float*)d_out);
}